// Round 17
// baseline (204.652 us; speedup 1.0000x reference)
//
#include <hip/hip_runtime.h>

// TriPlane sampling, 64^3 Morton counting-sort (rank-recorded), bf16 planes.
// 6 dispatches:
//  (1) zero_cells
//  (2) transpose_hist: planes [C,H,W]f32 -> [H,W,C]bf16 + rank-recording hist
//  (3) scan_local: 256 blocks x 1024 cells, in-place local exclusive scan
//  (4) scan_top: 1 block scans the 256 block totals
//  (5) scatter: pos = local[cell] + btot[cell>>10] + rank  (no atomics)
//  (6) triplane_sample: dense sorted order, 1024-thread blocks (128 pts) to
//      maximize resident waves/CU (R16 showed ILP can't buy MLP; TLP must).

#define CDIM 32
#define SGRID 64
#define NCELL (SGRID * SGRID * SGRID)   // 262144
#define CHW 10000
#define FHW 160000
#define CBLK 157           // ceil(10000/64)
#define FBLK 2500          // 160000/64
#define TRB (3 * CBLK + 3 * FBLK)
#define SCANB 256          // local-scan blocks; 1024 cells each

typedef float  nfloat4 __attribute__((ext_vector_type(4)));  // nontemporal-safe

struct PlanePtrs { const float* p[6]; };

__device__ __forceinline__ unsigned bf16rn(float f) {  // RNE f32->bf16 bits
    unsigned u = __float_as_uint(f);
    return (u + 0x7FFFu + ((u >> 16) & 1u)) >> 16;
}

// ---- Morton cell index (6 bits per axis) ----
__device__ __forceinline__ int spread3(int v) {
    v = (v | (v << 16)) & 0x030000FF;
    v = (v | (v << 8))  & 0x0300F00F;
    v = (v | (v << 4))  & 0x030C30C3;
    v = (v | (v << 2))  & 0x09249249;
    return v;
}

__device__ __forceinline__ int cell_of(float x, float y, float z) {
    int cx = (int)((x + 4.0f) * 8.0f);   // 8 world units -> 64 cells
    int cy = (int)((y + 4.0f) * 8.0f);
    int cz = (int)((z + 4.0f) * 8.0f);
    cx = min(SGRID - 1, max(0, cx));
    cy = min(SGRID - 1, max(0, cy));
    cz = min(SGRID - 1, max(0, cz));
    return spread3(cx) | (spread3(cy) << 1) | (spread3(cz) << 2);
}

__global__ void zero_cells(int4* __restrict__ cells4) {
    int i = blockIdx.x * blockDim.x + threadIdx.x;   // 65536 int4
    cells4[i] = make_int4(0, 0, 0, 0);
}

// ---- fused: blocks [0,TRB) transpose planes to bf16; rest do rank-hist ----
__global__ void transpose_hist(PlanePtrs in, unsigned* __restrict__ outp,
                               const float* __restrict__ xyz,
                               int* __restrict__ cells,
                               unsigned* __restrict__ cellrank, int n) {
    __shared__ float lds[64][33];
    int b = blockIdx.x;
    int tid = threadIdx.x;

    if (b >= TRB) {
        // ---- histogram with rank recording: 4 points/thread ----
        int t = (b - TRB) * 256 + tid;
        int i0 = t * 4;
        if (i0 >= n) return;
        const nfloat4* x4 = (const nfloat4*)xyz;
        nfloat4 v0 = __builtin_nontemporal_load(&x4[t * 3 + 0]);
        nfloat4 v1 = __builtin_nontemporal_load(&x4[t * 3 + 1]);
        nfloat4 v2 = __builtin_nontemporal_load(&x4[t * 3 + 2]);
        float px[4] = {v0.x, v0.w, v1.z, v2.y};
        float py[4] = {v0.y, v1.x, v1.w, v2.z};
        float pz[4] = {v0.z, v1.y, v2.x, v2.w};
        unsigned cr[4];
#pragma unroll
        for (int k = 0; k < 4; ++k) {
            int i = i0 + k;
            if (i < n) {
                int cell = cell_of(px[k], py[k], pz[k]);
                int r = atomicAdd(&cells[cell], 1);   // rank within cell
                cr[k] = ((unsigned)cell << 10) | (unsigned)r;
            }
        }
        if (i0 + 3 < n) {
            uint4 w = make_uint4(cr[0], cr[1], cr[2], cr[3]);
            *(uint4*)(cellrank + i0) = w;
        } else {
            for (int k = 0; k < 4 && i0 + k < n; ++k) cellrank[i0 + k] = cr[k];
        }
        return;
    }

    // ---- transpose [32,HW]f32 -> [HW,32]bf16 ----
    const size_t CSZ = (size_t)CHW * CDIM;
    const size_t FSZ = (size_t)FHW * CDIM;
    const float* src;
    unsigned* dst;   // packed bf16 pairs (uint = 2 channels)
    int HW, local;
    if (b < 3 * CBLK) {
        int plane = b / CBLK; local = b - plane * CBLK;
        src = in.p[plane];
        dst = outp + (size_t)plane * (CSZ / 2);
        HW = CHW;
    } else {
        b -= 3 * CBLK;
        int plane = b / FBLK; local = b - plane * FBLK;
        src = in.p[3 + plane];
        dst = outp + (3 * CSZ + (size_t)plane * FSZ) / 2;
        HW = FHW;
    }

    int p0 = local * 64;
    int pi = tid & 63;
    int cg = tid >> 6;
#pragma unroll
    for (int i = 0; i < 8; ++i) {
        int c = cg * 8 + i;
        int p = p0 + pi;
        float v = (p < HW) ? src[(size_t)c * HW + p] : 0.0f;
        lds[pi][c] = v;
    }
    __syncthreads();
    int cp = tid & 15;           // channel pair 0..15
    int pj = tid >> 4;           // 0..15
#pragma unroll
    for (int i = 0; i < 4; ++i) {
        int p = pj + i * 16;     // 0..63
        if (p0 + p < HW) {
            unsigned lo = bf16rn(lds[p][2 * cp]);
            unsigned hi = bf16rn(lds[p][2 * cp + 1]);
            dst[(size_t)(p0 + p) * 16 + cp] = lo | (hi << 16);
        }
    }
}

// ---- local exclusive scan: 256 blocks, 1024 cells each (4 per thread) ----
__global__ void scan_local(int* __restrict__ cells, int* __restrict__ btot) {
    __shared__ int lds[256];
    int t = threadIdx.x;
    int4* c4 = (int4*)cells + blockIdx.x * 256;   // this block's 1024 cells
    int4 v = c4[t];
    int s = v.x + v.y + v.z + v.w;
    lds[t] = s;
    __syncthreads();
    for (int off = 1; off < 256; off <<= 1) {
        int u = 0;
        if (t >= off) u = lds[t - off];
        __syncthreads();
        if (t >= off) lds[t] += u;
        __syncthreads();
    }
    if (t == 255) btot[blockIdx.x] = lds[255];
    int prefix = (t == 0) ? 0 : lds[t - 1];
    int a = v.x, bb = v.y, c = v.z, d = v.w;
    v.x = prefix;
    v.y = prefix + a;
    v.z = prefix + a + bb;
    v.w = prefix + a + bb + c;
    c4[t] = v;
}

// ---- top-level exclusive scan of 256 block totals ----
__global__ void scan_top(int* __restrict__ btot) {
    __shared__ int lds[256];
    int t = threadIdx.x;
    int v = btot[t];
    lds[t] = v;
    __syncthreads();
    for (int off = 1; off < 256; off <<= 1) {
        int u = 0;
        if (t >= off) u = lds[t - off];
        __syncthreads();
        if (t >= off) lds[t] += u;
        __syncthreads();
    }
    btot[t] = (t == 0) ? 0 : lds[t - 1];
}

// ---- scatter WITHOUT atomics: pos = local[cell] + btot[cell>>10] + rank ----
__global__ void scatter_kernel(const float* __restrict__ xyz,
                               const int* __restrict__ cells,
                               const int* __restrict__ btot,
                               const unsigned* __restrict__ cellrank,
                               float4* __restrict__ sortedg, int n) {
    int t = blockIdx.x * blockDim.x + threadIdx.x;
    int i0 = t * 4;
    if (i0 >= n) return;
    const nfloat4* x4 = (const nfloat4*)xyz;
    nfloat4 v0 = __builtin_nontemporal_load(&x4[t * 3 + 0]);
    nfloat4 v1 = __builtin_nontemporal_load(&x4[t * 3 + 1]);
    nfloat4 v2 = __builtin_nontemporal_load(&x4[t * 3 + 2]);
    uint4 cr4 = *(const uint4*)(cellrank + i0);
    float px[4] = {v0.x, v0.w, v1.z, v2.y};
    float py[4] = {v0.y, v1.x, v1.w, v2.z};
    float pz[4] = {v0.z, v1.y, v2.x, v2.w};
    unsigned crs[4] = {cr4.x, cr4.y, cr4.z, cr4.w};
#pragma unroll
    for (int k = 0; k < 4; ++k) {
        int i = i0 + k;
        if (i >= n) break;
        int cell = (int)(crs[k] >> 10);
        int rank = (int)(crs[k] & 1023u);
        int pos = cells[cell] + btot[cell >> 10] + rank;
        float4 v;
        v.x = (px[k] + 4.0f) * 0.25f - 1.0f;
        v.y = (py[k] + 4.0f) * 0.25f - 1.0f;
        v.z = (pz[k] + 4.0f) * 0.25f - 1.0f;
        v.w = __int_as_float(i);
        sortedg[pos] = v;
    }
}

// ---- bilinear corner addresses for one bf16 plane (8 channels/thread) ----
struct CornersB {
    const uint4 *p00, *p01, *p10, *p11;
    float wx, wy;
};

__device__ __forceinline__ CornersB mk_corners(const unsigned* __restrict__ base,
                                               int R, float u, float v, int c8) {
    float s = 0.5f * (float)(R - 1);
    float x = (u + 1.0f) * s;
    float y = (v + 1.0f) * s;
    float rm1 = (float)(R - 1);
    x = fminf(fmaxf(x, 0.0f), rm1);
    y = fminf(fmaxf(y, 0.0f), rm1);
    float x0f = floorf(x), y0f = floorf(y);
    int x0 = (int)x0f, y0 = (int)y0f;
    int x1 = min(x0 + 1, R - 1);
    int y1 = min(y0 + 1, R - 1);
    CornersB c;
    c.wx = x - x0f;
    c.wy = y - y0f;
    const unsigned* r0 = base + ((size_t)y0 * R) * 16 + c8 / 2;
    const unsigned* r1 = base + ((size_t)y1 * R) * 16 + c8 / 2;
    c.p00 = (const uint4*)(r0 + (size_t)x0 * 16);
    c.p01 = (const uint4*)(r0 + (size_t)x1 * 16);
    c.p10 = (const uint4*)(r1 + (size_t)x0 * 16);
    c.p11 = (const uint4*)(r1 + (size_t)x1 * 16);
    return c;
}

__device__ __forceinline__ void acc8(float* acc, uint4 u, float w) {
#pragma unroll
    for (int j = 0; j < 4; ++j) {
        unsigned word = (&u.x)[j];
        float lo = __uint_as_float(word << 16);
        float hi = __uint_as_float(word & 0xFFFF0000u);
        acc[2 * j]     += lo * w;
        acc[2 * j + 1] += hi * w;
    }
}

__device__ __forceinline__ void blend8(float* acc, uint4 a, uint4 b, uint4 c,
                                       uint4 d, float wx, float wy) {
    float w00 = (1.0f - wx) * (1.0f - wy);
    float w01 = wx * (1.0f - wy);
    float w10 = (1.0f - wx) * wy;
    float w11 = wx * wy;
    acc8(acc, a, w00);
    acc8(acc, b, w01);
    acc8(acc, c, w10);
    acc8(acc, d, w11);
}

// ---- sampler: 1024-thr blocks, 128 pts/block; each 64-lane wave LEVEL-PURE:
//      wave w (0..15): level = w&1, pts = base + (w>>1)*16 + (lane>>2),
//      channel slice c8 = (lane&3)*8. ----
__global__ __launch_bounds__(1024)
void triplane_sample(const float4* __restrict__ sortedg,
                     const unsigned* __restrict__ planes,
                     float* __restrict__ out, int n_pts) {
    int nwg  = gridDim.x;
    int orig = blockIdx.x;
    int xcd = orig & 7, local = orig >> 3;
    int q = nwg >> 3, r = nwg & 7;
    int wg = (xcd < r ? xcd * (q + 1) : r * (q + 1) + (xcd - r) * q) + local;

    int wave = (int)threadIdx.x >> 6;
    int lane = (int)threadIdx.x & 63;
    int level = wave & 1;
    int i = wg * 128 + (wave >> 1) * 16 + (lane >> 2);
    if (i >= n_pts) return;
    int c8 = (lane & 3) * 8;

    float4 g = sortedg[i];
    int n_orig = __float_as_int(g.w);

    const size_t CSZ2 = (size_t)CHW * CDIM / 2;   // uints per coarse plane
    const size_t FSZ2 = (size_t)FHW * CDIM / 2;
    const unsigned* base;
    int R;
    size_t psz;
    if (level == 0) { base = planes;            R = 100; psz = CSZ2; }
    else            { base = planes + 3 * CSZ2; R = 400; psz = FSZ2; }

    CornersB cxy = mk_corners(base,           R, g.x, g.y, c8);
    CornersB cxz = mk_corners(base + psz,     R, g.x, g.z, c8);
    CornersB cyz = mk_corners(base + 2 * psz, R, g.y, g.z, c8);

    uint4 a0 = *cxy.p00, a1 = *cxy.p01, a2 = *cxy.p10, a3 = *cxy.p11;
    uint4 b0 = *cxz.p00, b1 = *cxz.p01, b2 = *cxz.p10, b3 = *cxz.p11;
    uint4 d0 = *cyz.p00, d1 = *cyz.p01, d2 = *cyz.p10, d3 = *cyz.p11;

    float acc[8] = {0, 0, 0, 0, 0, 0, 0, 0};
    blend8(acc, a0, a1, a2, a3, cxy.wx, cxy.wy);
    blend8(acc, b0, b1, b2, b3, cxz.wx, cxz.wy);
    blend8(acc, d0, d1, d2, d3, cyz.wx, cyz.wy);

    float* o = out + (size_t)n_orig * 64 + level * 32 + c8;
    nfloat4 lo4 = {acc[0], acc[1], acc[2], acc[3]};
    nfloat4 hi4 = {acc[4], acc[5], acc[6], acc[7]};
    __builtin_nontemporal_store(lo4, (nfloat4*)o);
    __builtin_nontemporal_store(hi4, (nfloat4*)(o + 4));
}

extern "C" void kernel_launch(void* const* d_in, const int* in_sizes, int n_in,
                              void* d_out, int out_size, void* d_ws, size_t ws_size,
                              hipStream_t stream) {
    const float* xyz = (const float*)d_in[0];
    int n = in_sizes[0] / 3;

    const size_t CSZ = (size_t)CHW * CDIM;
    const size_t FSZ = (size_t)FHW * CDIM;
    const size_t PLANE_UINTS = (3 * CSZ + 3 * FSZ) / 2;   // packed bf16 pairs

    unsigned* planesb  = (unsigned*)d_ws;
    int*      cells    = (int*)(planesb + PLANE_UINTS);              // NCELL
    int*      btot     = cells + NCELL;                              // 256
    float4*   sortedg  = (float4*)((char*)(btot + 256) + 0);
    unsigned* cellrank = (unsigned*)((char*)sortedg + (size_t)n * 16);

    dim3 blk(256);
    PlanePtrs pp;
    for (int k = 0; k < 6; ++k) pp.p[k] = (const float*)d_in[1 + k];

    zero_cells<<<NCELL / 4 / 256, blk, 0, stream>>>((int4*)cells);

    int histblk = (n + 1023) / 1024;   // 4 pts/thread
    transpose_hist<<<TRB + histblk, blk, 0, stream>>>(pp, planesb, xyz, cells,
                                                      cellrank, n);

    scan_local<<<SCANB, blk, 0, stream>>>(cells, btot);
    scan_top<<<1, 256, 0, stream>>>(btot);
    scatter_kernel<<<histblk, blk, 0, stream>>>(xyz, cells, btot, cellrank,
                                                sortedg, n);

    int nblk = (n + 127) / 128;        // 128 points per 1024-thread block
    triplane_sample<<<nblk, dim3(1024), 0, stream>>>(sortedg, planesb,
                                                     (float*)d_out, n);
}

// Round 19
// 178.254 us; speedup vs baseline: 1.1481x; 1.1481x over previous
//
#include <hip/hip_runtime.h>

// TriPlane sampling, 64^3 Morton counting-sort (rank-recorded), bf16 planes.
// 5 dispatches:
//  (1) zero_cells
//  (2) transpose_hist: planes [C,H,W]f32 -> [H,W,C]bf16 + rank-recording hist
//  (3) scan_local: 256 blocks x 1024 cells, in-place local exclusive scan
//  (4) scatter: per-block LDS re-scan of 256 block totals (scan_top folded in);
//      pos = local[cell] + btot_prefix[cell>>10] + rank  (no atomics)
//  (5) triplane_sample: dense sorted order, 128-thr blocks (16 pts, ~24KB
//      corner footprint -> fits L1; R17 showed 1024-thr blocks thrash L1).

#define CDIM 32
#define SGRID 64
#define NCELL (SGRID * SGRID * SGRID)   // 262144
#define CHW 10000
#define FHW 160000
#define CBLK 157           // ceil(10000/64)
#define FBLK 2500          // 160000/64
#define TRB (3 * CBLK + 3 * FBLK)
#define SCANB 256          // local-scan blocks; 1024 cells each

typedef float  nfloat4 __attribute__((ext_vector_type(4)));  // nontemporal-safe

struct PlanePtrs { const float* p[6]; };

__device__ __forceinline__ unsigned bf16rn(float f) {  // RNE f32->bf16 bits
    unsigned u = __float_as_uint(f);
    return (u + 0x7FFFu + ((u >> 16) & 1u)) >> 16;
}

// ---- Morton cell index (6 bits per axis) ----
__device__ __forceinline__ int spread3(int v) {
    v = (v | (v << 16)) & 0x030000FF;
    v = (v | (v << 8))  & 0x0300F00F;
    v = (v | (v << 4))  & 0x030C30C3;
    v = (v | (v << 2))  & 0x09249249;
    return v;
}

__device__ __forceinline__ int cell_of(float x, float y, float z) {
    int cx = (int)((x + 4.0f) * 8.0f);   // 8 world units -> 64 cells
    int cy = (int)((y + 4.0f) * 8.0f);
    int cz = (int)((z + 4.0f) * 8.0f);
    cx = min(SGRID - 1, max(0, cx));
    cy = min(SGRID - 1, max(0, cy));
    cz = min(SGRID - 1, max(0, cz));
    return spread3(cx) | (spread3(cy) << 1) | (spread3(cz) << 2);
}

__global__ void zero_cells(int4* __restrict__ cells4) {
    int i = blockIdx.x * blockDim.x + threadIdx.x;   // 65536 int4
    cells4[i] = make_int4(0, 0, 0, 0);
}

// ---- fused: blocks [0,TRB) transpose planes to bf16; rest do rank-hist ----
__global__ void transpose_hist(PlanePtrs in, unsigned* __restrict__ outp,
                               const float* __restrict__ xyz,
                               int* __restrict__ cells,
                               unsigned* __restrict__ cellrank, int n) {
    __shared__ float lds[64][33];
    int b = blockIdx.x;
    int tid = threadIdx.x;

    if (b >= TRB) {
        // ---- histogram with rank recording: 4 points/thread ----
        int t = (b - TRB) * 256 + tid;
        int i0 = t * 4;
        if (i0 >= n) return;
        const nfloat4* x4 = (const nfloat4*)xyz;
        nfloat4 v0 = __builtin_nontemporal_load(&x4[t * 3 + 0]);
        nfloat4 v1 = __builtin_nontemporal_load(&x4[t * 3 + 1]);
        nfloat4 v2 = __builtin_nontemporal_load(&x4[t * 3 + 2]);
        float px[4] = {v0.x, v0.w, v1.z, v2.y};
        float py[4] = {v0.y, v1.x, v1.w, v2.z};
        float pz[4] = {v0.z, v1.y, v2.x, v2.w};
        unsigned cr[4];
#pragma unroll
        for (int k = 0; k < 4; ++k) {
            int i = i0 + k;
            if (i < n) {
                int cell = cell_of(px[k], py[k], pz[k]);
                int r = atomicAdd(&cells[cell], 1);   // rank within cell
                cr[k] = ((unsigned)cell << 10) | (unsigned)r;
            }
        }
        if (i0 + 3 < n) {
            uint4 w = make_uint4(cr[0], cr[1], cr[2], cr[3]);
            *(uint4*)(cellrank + i0) = w;
        } else {
            for (int k = 0; k < 4 && i0 + k < n; ++k) cellrank[i0 + k] = cr[k];
        }
        return;
    }

    // ---- transpose [32,HW]f32 -> [HW,32]bf16 ----
    const size_t CSZ = (size_t)CHW * CDIM;
    const size_t FSZ = (size_t)FHW * CDIM;
    const float* src;
    unsigned* dst;   // packed bf16 pairs (uint = 2 channels)
    int HW, local;
    if (b < 3 * CBLK) {
        int plane = b / CBLK; local = b - plane * CBLK;
        src = in.p[plane];
        dst = outp + (size_t)plane * (CSZ / 2);
        HW = CHW;
    } else {
        b -= 3 * CBLK;
        int plane = b / FBLK; local = b - plane * FBLK;
        src = in.p[3 + plane];
        dst = outp + (3 * CSZ + (size_t)plane * FSZ) / 2;
        HW = FHW;
    }

    int p0 = local * 64;
    int pi = tid & 63;
    int cg = tid >> 6;
#pragma unroll
    for (int i = 0; i < 8; ++i) {
        int c = cg * 8 + i;
        int p = p0 + pi;
        float v = (p < HW) ? src[(size_t)c * HW + p] : 0.0f;
        lds[pi][c] = v;
    }
    __syncthreads();
    int cp = tid & 15;           // channel pair 0..15
    int pj = tid >> 4;           // 0..15
#pragma unroll
    for (int i = 0; i < 4; ++i) {
        int p = pj + i * 16;     // 0..63
        if (p0 + p < HW) {
            unsigned lo = bf16rn(lds[p][2 * cp]);
            unsigned hi = bf16rn(lds[p][2 * cp + 1]);
            dst[(size_t)(p0 + p) * 16 + cp] = lo | (hi << 16);
        }
    }
}

// ---- local exclusive scan: 256 blocks, 1024 cells each (4 per thread) ----
__global__ void scan_local(int* __restrict__ cells, int* __restrict__ btot) {
    __shared__ int lds[256];
    int t = threadIdx.x;
    int4* c4 = (int4*)cells + blockIdx.x * 256;   // this block's 1024 cells
    int4 v = c4[t];
    int s = v.x + v.y + v.z + v.w;
    lds[t] = s;
    __syncthreads();
    for (int off = 1; off < 256; off <<= 1) {
        int u = 0;
        if (t >= off) u = lds[t - off];
        __syncthreads();
        if (t >= off) lds[t] += u;
        __syncthreads();
    }
    if (t == 255) btot[blockIdx.x] = lds[255];
    int prefix = (t == 0) ? 0 : lds[t - 1];
    int a = v.x, bb = v.y, c = v.z, d = v.w;
    v.x = prefix;
    v.y = prefix + a;
    v.z = prefix + a + bb;
    v.w = prefix + a + bb + c;
    c4[t] = v;
}

// ---- scatter, scan_top folded in: each block re-scans the 256 totals ----
__global__ void scatter_kernel(const float* __restrict__ xyz,
                               const int* __restrict__ cells,
                               const int* __restrict__ btot,
                               const unsigned* __restrict__ cellrank,
                               float4* __restrict__ sortedg, int n) {
    __shared__ int sb[256];
    int tid = threadIdx.x;
    // exclusive scan of btot[0..255] in LDS (every block, cheap)
    sb[tid] = btot[tid];
    __syncthreads();
    for (int off = 1; off < 256; off <<= 1) {
        int u = 0;
        if (tid >= off) u = sb[tid - off];
        __syncthreads();
        if (tid >= off) sb[tid] += u;
        __syncthreads();
    }
    // sb now inclusive; exclusive prefix of chunk c is (c==0)?0:sb[c-1]

    int t = blockIdx.x * blockDim.x + tid;
    int i0 = t * 4;
    if (i0 >= n) return;
    const nfloat4* x4 = (const nfloat4*)xyz;
    nfloat4 v0 = __builtin_nontemporal_load(&x4[t * 3 + 0]);
    nfloat4 v1 = __builtin_nontemporal_load(&x4[t * 3 + 1]);
    nfloat4 v2 = __builtin_nontemporal_load(&x4[t * 3 + 2]);
    uint4 cr4 = *(const uint4*)(cellrank + i0);
    float px[4] = {v0.x, v0.w, v1.z, v2.y};
    float py[4] = {v0.y, v1.x, v1.w, v2.z};
    float pz[4] = {v0.z, v1.y, v2.x, v2.w};
    unsigned crs[4] = {cr4.x, cr4.y, cr4.z, cr4.w};
#pragma unroll
    for (int k = 0; k < 4; ++k) {
        int i = i0 + k;
        if (i >= n) break;
        int cell  = (int)(crs[k] >> 10);
        int rank  = (int)(crs[k] & 1023u);
        int chunk = cell >> 10;
        int cbase = (chunk == 0) ? 0 : sb[chunk - 1];
        int pos = cells[cell] + cbase + rank;
        float4 v;
        v.x = (px[k] + 4.0f) * 0.25f - 1.0f;
        v.y = (py[k] + 4.0f) * 0.25f - 1.0f;
        v.z = (pz[k] + 4.0f) * 0.25f - 1.0f;
        v.w = __int_as_float(i);
        sortedg[pos] = v;
    }
}

// ---- bilinear corner addresses for one bf16 plane (8 channels/thread) ----
struct CornersB {
    const uint4 *p00, *p01, *p10, *p11;
    float wx, wy;
};

__device__ __forceinline__ CornersB mk_corners(const unsigned* __restrict__ base,
                                               int R, float u, float v, int c8) {
    float s = 0.5f * (float)(R - 1);
    float x = (u + 1.0f) * s;
    float y = (v + 1.0f) * s;
    float rm1 = (float)(R - 1);
    x = fminf(fmaxf(x, 0.0f), rm1);
    y = fminf(fmaxf(y, 0.0f), rm1);
    float x0f = floorf(x), y0f = floorf(y);
    int x0 = (int)x0f, y0 = (int)y0f;
    int x1 = min(x0 + 1, R - 1);
    int y1 = min(y0 + 1, R - 1);
    CornersB c;
    c.wx = x - x0f;
    c.wy = y - y0f;
    const unsigned* r0 = base + ((size_t)y0 * R) * 16 + c8 / 2;
    const unsigned* r1 = base + ((size_t)y1 * R) * 16 + c8 / 2;
    c.p00 = (const uint4*)(r0 + (size_t)x0 * 16);
    c.p01 = (const uint4*)(r0 + (size_t)x1 * 16);
    c.p10 = (const uint4*)(r1 + (size_t)x0 * 16);
    c.p11 = (const uint4*)(r1 + (size_t)x1 * 16);
    return c;
}

__device__ __forceinline__ void acc8(float* acc, uint4 u, float w) {
#pragma unroll
    for (int j = 0; j < 4; ++j) {
        unsigned word = (&u.x)[j];
        float lo = __uint_as_float(word << 16);
        float hi = __uint_as_float(word & 0xFFFF0000u);
        acc[2 * j]     += lo * w;
        acc[2 * j + 1] += hi * w;
    }
}

__device__ __forceinline__ void blend8(float* acc, uint4 a, uint4 b, uint4 c,
                                       uint4 d, float wx, float wy) {
    float w00 = (1.0f - wx) * (1.0f - wy);
    float w01 = wx * (1.0f - wy);
    float w10 = (1.0f - wx) * wy;
    float w11 = wx * wy;
    acc8(acc, a, w00);
    acc8(acc, b, w01);
    acc8(acc, c, w10);
    acc8(acc, d, w11);
}

// ---- sampler: 128-thr blocks, 16 pts/block; wave 0 = coarse, wave 1 = fine.
//      16 pts x 12 corners x 64B ~ 24KB footprint -> L1-resident. ----
__global__ __launch_bounds__(128)
void triplane_sample(const float4* __restrict__ sortedg,
                     const unsigned* __restrict__ planes,
                     float* __restrict__ out, int n_pts) {
    int nwg  = gridDim.x;
    int orig = blockIdx.x;
    int xcd = orig & 7, local = orig >> 3;
    int q = nwg >> 3, r = nwg & 7;
    int wg = (xcd < r ? xcd * (q + 1) : r * (q + 1) + (xcd - r) * q) + local;

    int wave = (int)threadIdx.x >> 6;    // 0..1
    int lane = (int)threadIdx.x & 63;
    int level = wave;
    int i = wg * 16 + (lane >> 2);
    if (i >= n_pts) return;
    int c8 = (lane & 3) * 8;

    float4 g = sortedg[i];
    int n_orig = __float_as_int(g.w);

    const size_t CSZ2 = (size_t)CHW * CDIM / 2;   // uints per coarse plane
    const size_t FSZ2 = (size_t)FHW * CDIM / 2;
    const unsigned* base;
    int R;
    size_t psz;
    if (level == 0) { base = planes;            R = 100; psz = CSZ2; }
    else            { base = planes + 3 * CSZ2; R = 400; psz = FSZ2; }

    CornersB cxy = mk_corners(base,           R, g.x, g.y, c8);
    CornersB cxz = mk_corners(base + psz,     R, g.x, g.z, c8);
    CornersB cyz = mk_corners(base + 2 * psz, R, g.y, g.z, c8);

    uint4 a0 = *cxy.p00, a1 = *cxy.p01, a2 = *cxy.p10, a3 = *cxy.p11;
    uint4 b0 = *cxz.p00, b1 = *cxz.p01, b2 = *cxz.p10, b3 = *cxz.p11;
    uint4 d0 = *cyz.p00, d1 = *cyz.p01, d2 = *cyz.p10, d3 = *cyz.p11;

    float acc[8] = {0, 0, 0, 0, 0, 0, 0, 0};
    blend8(acc, a0, a1, a2, a3, cxy.wx, cxy.wy);
    blend8(acc, b0, b1, b2, b3, cxz.wx, cxz.wy);
    blend8(acc, d0, d1, d2, d3, cyz.wx, cyz.wy);

    float* o = out + (size_t)n_orig * 64 + level * 32 + c8;
    nfloat4 lo4 = {acc[0], acc[1], acc[2], acc[3]};
    nfloat4 hi4 = {acc[4], acc[5], acc[6], acc[7]};
    __builtin_nontemporal_store(lo4, (nfloat4*)o);
    __builtin_nontemporal_store(hi4, (nfloat4*)(o + 4));
}

extern "C" void kernel_launch(void* const* d_in, const int* in_sizes, int n_in,
                              void* d_out, int out_size, void* d_ws, size_t ws_size,
                              hipStream_t stream) {
    const float* xyz = (const float*)d_in[0];
    int n = in_sizes[0] / 3;

    const size_t CSZ = (size_t)CHW * CDIM;
    const size_t FSZ = (size_t)FHW * CDIM;
    const size_t PLANE_UINTS = (3 * CSZ + 3 * FSZ) / 2;   // packed bf16 pairs

    unsigned* planesb  = (unsigned*)d_ws;
    int*      cells    = (int*)(planesb + PLANE_UINTS);              // NCELL
    int*      btot     = cells + NCELL;                              // 256
    float4*   sortedg  = (float4*)((char*)(btot + 256) + 0);
    unsigned* cellrank = (unsigned*)((char*)sortedg + (size_t)n * 16);

    dim3 blk(256);
    PlanePtrs pp;
    for (int k = 0; k < 6; ++k) pp.p[k] = (const float*)d_in[1 + k];

    zero_cells<<<NCELL / 4 / 256, blk, 0, stream>>>((int4*)cells);

    int histblk = (n + 1023) / 1024;   // 4 pts/thread
    transpose_hist<<<TRB + histblk, blk, 0, stream>>>(pp, planesb, xyz, cells,
                                                      cellrank, n);

    scan_local<<<SCANB, blk, 0, stream>>>(cells, btot);
    scatter_kernel<<<histblk, blk, 0, stream>>>(xyz, cells, btot, cellrank,
                                                sortedg, n);

    int nblk = (n + 15) / 16;          // 16 points per 128-thread block
    triplane_sample<<<nblk, dim3(128), 0, stream>>>(sortedg, planesb,
                                                    (float*)d_out, n);
}